// Round 1
// baseline (259.400 us; speedup 1.0000x reference)
//
#include <hip/hip_runtime.h>
#include <stdint.h>

#define NSEQ 1032
#define CDIM 1024
#define HD 64
#define H_HEADS 16
#define BROWS 4128
#define SCALE 0.125f

typedef __attribute__((ext_vector_type(8))) short bf16x8;
typedef __attribute__((ext_vector_type(4))) float f32x4;

__device__ __forceinline__ unsigned short f2bf(float f) {
  union { float f; uint32_t u; } c; c.f = f;
  uint32_t u = c.u;
  return (unsigned short)((u + 0x7fffu + ((u >> 16) & 1u)) >> 16);
}

__device__ __forceinline__ void gl16(const void* gp, void* lp) {
  __builtin_amdgcn_global_load_lds((const __attribute__((address_space(1))) void*)gp,
                                   (__attribute__((address_space(3))) void*)lp, 16, 0, 0);
}

__global__ void convert_f32_bf16(const float* __restrict__ src, unsigned short* __restrict__ dst, int n4) {
  int i = blockIdx.x * blockDim.x + threadIdx.x;
  if (i >= n4) return;
  float4 v = ((const float4*)src)[i];
  ushort4 o;
  o.x = f2bf(v.x); o.y = f2bf(v.y); o.z = f2bf(v.z); o.w = f2bf(v.w);
  ((ushort4*)dst)[i] = o;
}

// C[m][j] = sum_k A[m][k] * Bw[j][k] + bias[j]
// MODE 0: scatter to K [64][1032][64] and V^T [64][64][1032] (bf16)
// MODE 1: write fp32 out [M][1024]
template<int MODE>
__global__ __launch_bounds__(256, 2) void gemm_bt(
    const unsigned short* __restrict__ A,
    const unsigned short* __restrict__ Bw,
    const float* __restrict__ bias,
    unsigned short* __restrict__ outK,
    unsigned short* __restrict__ outV,
    float* __restrict__ outF,
    int M, int K)
{
  __shared__ unsigned short As[128 * 32];
  __shared__ unsigned short Bs[128 * 32];
  const int t = threadIdx.x;
  const int w = t >> 6, lane = t & 63, lr = lane & 15, lg = lane >> 4;
  const int wr = w >> 1, wc = w & 1;
  const int m0 = blockIdx.y * 128, n0 = blockIdx.x * 128;
  f32x4 acc[4][4] = {};

  for (int ks = 0; ks < K; ks += 32) {
    #pragma unroll
    for (int q = 0; q < 2; ++q) {
      const int o = t + (q << 8);          // 16B chunk id 0..511
      const int row = o >> 2, kc = o & 3;  // 128 rows x 4 chunks
      int ra = m0 + row; ra = ra < M ? ra : M - 1;
      gl16(A + (size_t)ra * K + ks + kc * 8, (void*)(As + o * 8));
      gl16(Bw + (size_t)(n0 + row) * K + ks + kc * 8, (void*)(Bs + o * 8));
    }
    __syncthreads();
    bf16x8 af[4], bfr[4];
    #pragma unroll
    for (int m = 0; m < 4; ++m)
      af[m] = *(const bf16x8*)(As + (wr * 64 + m * 16 + lr) * 32 + lg * 8);
    #pragma unroll
    for (int n = 0; n < 4; ++n)
      bfr[n] = *(const bf16x8*)(Bs + (wc * 64 + n * 16 + lr) * 32 + lg * 8);
    #pragma unroll
    for (int m = 0; m < 4; ++m)
      #pragma unroll
      for (int n = 0; n < 4; ++n)
        acc[m][n] = __builtin_amdgcn_mfma_f32_16x16x32_bf16(af[m], bfr[n], acc[m][n], 0, 0, 0);
    __syncthreads();
  }

  #pragma unroll
  for (int m = 0; m < 4; ++m) {
    const int rowb = m0 + wr * 64 + m * 16 + lg * 4;
    #pragma unroll
    for (int n = 0; n < 4; ++n) {
      const int col = n0 + wc * 64 + n * 16 + lr;
      const float bv = bias[col];
      #pragma unroll
      for (int r = 0; r < 4; ++r) {
        const int row = rowb + r;
        if (row >= M) continue;
        const float v = acc[m][n][r] + bv;
        if (MODE == 0) {
          const int b = row / NSEQ, nn = row - b * NSEQ;
          if (col < CDIM) {
            const int h = col >> 6, d = col & 63;
            outK[((size_t)(b * H_HEADS + h) * NSEQ + nn) * HD + d] = f2bf(v);
          } else {
            const int jj = col - CDIM, h = jj >> 6, d = jj & 63;
            outV[((size_t)(b * H_HEADS + h) * HD + d) * NSEQ + nn] = f2bf(v);
          }
        } else {
          outF[(size_t)row * CDIM + col] = v;
        }
      }
    }
  }
}

// One block: (head bh, row-tile rt). 4 waves x 16 rows. Streams 17 col-tiles of 64.
__global__ __launch_bounds__(256, 2) void attn_kernel(
    const unsigned short* __restrict__ Kb,   // [64][1032][64] bf16
    const unsigned short* __restrict__ Vt,   // [64][64][1032] bf16
    const float* __restrict__ addm,          // [1032][1032]
    const float* __restrict__ rcs,           // [64][1032][1032]
    unsigned short* __restrict__ outp)       // [4128][1024] bf16
{
  __shared__ unsigned short Kc[64 * 72];  // [m][d], padded stride 72
  __shared__ unsigned short Vs[64 * 72];  // [d][m], padded stride 72
  __shared__ unsigned short Ps[64 * 72];  // [i][m], padded stride 72
  const int t = threadIdx.x;
  const int w = t >> 6, lane = t & 63, lr = lane & 15, lg = lane >> 4;
  const int bh = blockIdx.y;
  const int rt = blockIdx.x;
  const int i_base = rt * 64 + w * 16;

  // hoist Kr A-fragments (rows i_base..i_base+15, d 0..63)
  bf16x8 akr[2];
  {
    int row = i_base + lr; if (row > NSEQ - 1) row = NSEQ - 1;
    const unsigned short* p = Kb + ((size_t)bh * NSEQ + row) * HD + lg * 8;
    akr[0] = *(const bf16x8*)(p);
    akr[1] = *(const bf16x8*)(p + 32);
  }

  f32x4 accP[4] = {};
  f32x4 accR[4] = {};
  float lsum[4] = {0.f, 0.f, 0.f, 0.f};

  for (int mt = 0; mt < 17; ++mt) {
    const int mB = mt * 64;
    // stage Kc[m][d] and Vs[d][m]
    #pragma unroll
    for (int q = 0; q < 2; ++q) {
      const int o = t + (q << 8);          // 0..511, 64 rows x 8 chunks
      const int row = o >> 3, ch = o & 7;
      int mrow = mB + row; if (mrow > NSEQ - 1) mrow = NSEQ - 1;
      bf16x8 kv = *(const bf16x8*)(Kb + ((size_t)bh * NSEQ + mrow) * HD + ch * 8);
      *(bf16x8*)(Kc + row * 72 + ch * 8) = kv;
      int cb = mB + ch * 8; if (cb + 8 > NSEQ) cb = NSEQ - 8;
      bf16x8 vv = *(const bf16x8*)(Vt + ((size_t)bh * HD + row) * NSEQ + cb);
      *(bf16x8*)(Vs + row * 72 + ch * 8) = vv;
    }
    __syncthreads();

    // S = Kr @ Kc^T  (16 x 64 per wave)
    f32x4 s[4];
    #pragma unroll
    for (int fn = 0; fn < 4; ++fn) {
      f32x4 z = {0.f, 0.f, 0.f, 0.f};
      bf16x8 b0 = *(const bf16x8*)(Kc + (16 * fn + lr) * 72 + lg * 8);
      bf16x8 b1 = *(const bf16x8*)(Kc + (16 * fn + lr) * 72 + 32 + lg * 8);
      z = __builtin_amdgcn_mfma_f32_16x16x32_bf16(akr[0], b0, z, 0, 0, 0);
      z = __builtin_amdgcn_mfma_f32_16x16x32_bf16(akr[1], b1, z, 0, 0, 0);
      s[fn] = z;
    }

    // p = exp(scale*s + add); accumulate row sums; stash bf16 P in LDS
    const int irow_base = i_base + lg * 4;
    #pragma unroll
    for (int fn = 0; fn < 4; ++fn) {
      const int mcol = mB + 16 * fn + lr;
      const int mc = mcol > NSEQ - 1 ? NSEQ - 1 : mcol;
      #pragma unroll
      for (int r = 0; r < 4; ++r) {
        int irow = irow_base + r; int ic = irow > NSEQ - 1 ? NSEQ - 1 : irow;
        float sv = s[fn][r] * SCALE + addm[(size_t)ic * NSEQ + mc];
        float p = (mcol < NSEQ) ? __expf(sv) : 0.f;
        lsum[r] += p;
        Ps[(w * 16 + lg * 4 + r) * 72 + 16 * fn + lr] = f2bf(p);
      }
    }

    // rcs A-fragments straight from global (rows = lr, k contiguous 8)
    bf16x8 pr[2];
    {
      int irow = i_base + lr; int ic = irow > NSEQ - 1 ? NSEQ - 1 : irow;
      const float* rp = rcs + ((size_t)bh * NSEQ + ic) * NSEQ;
      #pragma unroll
      for (int ksf = 0; ksf < 2; ++ksf) {
        const int cb = mB + ksf * 32 + lg * 8;
        bf16x8 f;
        if (cb + 8 <= NSEQ) {
          float4 v0 = *(const float4*)(rp + cb);
          float4 v1 = *(const float4*)(rp + cb + 4);
          f[0] = (short)f2bf(v0.x); f[1] = (short)f2bf(v0.y);
          f[2] = (short)f2bf(v0.z); f[3] = (short)f2bf(v0.w);
          f[4] = (short)f2bf(v1.x); f[5] = (short)f2bf(v1.y);
          f[6] = (short)f2bf(v1.z); f[7] = (short)f2bf(v1.w);
        } else {
          #pragma unroll
          for (int j = 0; j < 8; ++j) f[j] = 0;
        }
        pr[ksf] = f;
      }
    }

    // PV: accP += P @ V, accR += RCS @ V
    bf16x8 pa0 = *(const bf16x8*)(Ps + (w * 16 + lr) * 72 + lg * 8);
    bf16x8 pa1 = *(const bf16x8*)(Ps + (w * 16 + lr) * 72 + 32 + lg * 8);
    #pragma unroll
    for (int fd = 0; fd < 4; ++fd) {
      bf16x8 v0 = *(const bf16x8*)(Vs + (16 * fd + lr) * 72 + lg * 8);
      bf16x8 v1 = *(const bf16x8*)(Vs + (16 * fd + lr) * 72 + 32 + lg * 8);
      accP[fd] = __builtin_amdgcn_mfma_f32_16x16x32_bf16(pa0, v0, accP[fd], 0, 0, 0);
      accP[fd] = __builtin_amdgcn_mfma_f32_16x16x32_bf16(pa1, v1, accP[fd], 0, 0, 0);
      accR[fd] = __builtin_amdgcn_mfma_f32_16x16x32_bf16(pr[0], v0, accR[fd], 0, 0, 0);
      accR[fd] = __builtin_amdgcn_mfma_f32_16x16x32_bf16(pr[1], v1, accR[fd], 0, 0, 0);
    }
    __syncthreads();
  }

  // reduce lsum across the 16 lanes of this row-group (cols 0..15 per lane)
  #pragma unroll
  for (int r = 0; r < 4; ++r) {
    float v = lsum[r];
    v += __shfl_xor(v, 1); v += __shfl_xor(v, 2);
    v += __shfl_xor(v, 4); v += __shfl_xor(v, 8);
    lsum[r] = v;
  }

  const int b = bh >> 4, hh = bh & 15;
  #pragma unroll
  for (int fd = 0; fd < 4; ++fd) {
    #pragma unroll
    for (int r = 0; r < 4; ++r) {
      const int irow = i_base + lg * 4 + r;
      if (irow < NSEQ) {
        const float val = 0.8f * accP[fd][r] / lsum[r] + 1.2f * accR[fd][r];
        outp[(size_t)(b * NSEQ + irow) * CDIM + hh * 64 + 16 * fd + lr] = f2bf(val);
      }
    }
  }
}

extern "C" void kernel_launch(void* const* d_in, const int* in_sizes, int n_in,
                              void* d_out, int out_size, void* d_ws, size_t ws_size,
                              hipStream_t stream) {
  (void)in_sizes; (void)n_in; (void)out_size; (void)ws_size;
  const float* x      = (const float*)d_in[0];
  const float* qkv_w  = (const float*)d_in[1];
  const float* qkv_b  = (const float*)d_in[2];
  const float* proj_w = (const float*)d_in[3];
  const float* proj_b = (const float*)d_in[4];
  const float* addm   = (const float*)d_in[5];
  const float* rcs    = (const float*)d_in[6];
  float* out = (float*)d_out;

  char* ws = (char*)d_ws;
  unsigned short* x_bf = (unsigned short*)ws; ws += (size_t)BROWS * CDIM * 2;
  unsigned short* wkv  = (unsigned short*)ws; ws += (size_t)2048 * CDIM * 2;
  unsigned short* wp   = (unsigned short*)ws; ws += (size_t)1024 * CDIM * 2;
  unsigned short* Kb   = (unsigned short*)ws; ws += (size_t)64 * NSEQ * HD * 2;
  unsigned short* Vt   = (unsigned short*)ws; ws += (size_t)64 * HD * NSEQ * 2;
  unsigned short* op   = (unsigned short*)ws; ws += (size_t)BROWS * CDIM * 2;

  const int n1 = BROWS * CDIM / 4, n2 = 2048 * CDIM / 4, n3 = 1024 * CDIM / 4;
  convert_f32_bf16<<<(n1 + 255) / 256, 256, 0, stream>>>(x, x_bf, n1);
  convert_f32_bf16<<<(n2 + 255) / 256, 256, 0, stream>>>(qkv_w + 1024 * 1024, wkv, n2);
  convert_f32_bf16<<<(n3 + 255) / 256, 256, 0, stream>>>(proj_w, wp, n3);

  // K/V projection (q is unused by the reference math — skipped)
  gemm_bt<0><<<dim3(16, 33), 256, 0, stream>>>(x_bf, wkv, qkv_b + 1024, Kb, Vt, nullptr, BROWS, CDIM);
  attn_kernel<<<dim3(17, 64), 256, 0, stream>>>(Kb, Vt, addm, rcs, op);
  gemm_bt<1><<<dim3(8, 33), 256, 0, stream>>>(op, wp, proj_b, nullptr, nullptr, out, BROWS, CDIM);
}